// Round 7
// baseline (130.435 us; speedup 1.0000x reference)
//
#include <hip/hip_runtime.h>
#include <math.h>
#include <stdint.h>

#define BATCH 128
#define DIN   1024
#define DOUT  1024
#define NO    16     // o-rows per wave
#define DEPTH 2      // double-buffered LDS slots per wave

// ---------- helpers ----------
__device__ __forceinline__ float softplus_f(float v) {
    return fmaxf(v, 0.0f) + log1pf(__expf(-fabsf(v)));
}

__device__ __forceinline__ unsigned bf16_rne(float f) {
    unsigned u = __float_as_uint(f);
    return (u + 0x7FFFu + ((u >> 16) & 1u)) >> 16;
}

// 16-byte-wide async global->LDS DMA (wave-uniform LDS base + lane*16,
// per-lane global source). Bypasses the VGPR load-return path.
__device__ __forceinline__ void stage16(const void* gsrc, void* ldst) {
    __builtin_amdgcn_global_load_lds(
        (const __attribute__((address_space(1))) uint32_t*)gsrc,
        (__attribute__((address_space(3))) uint32_t*)ldst,
        16, 0, 0);
}

// ---------- pass 1: pack (mu, softplus(rho)) as bf16 pairs ----------
// qm[o*DIN+i] = (bf16(softplus(rho)) << 16) | bf16(mu); bsp[o] = softplus(brho[o]).
__global__ __launch_bounds__(256) void pack_qm_kernel(
    const float* __restrict__ wmu,
    const float* __restrict__ wrho,
    const float* __restrict__ brho,
    unsigned* __restrict__ qm,
    float* __restrict__ bsp)
{
    const int idx = blockIdx.x * 256 + threadIdx.x;  // float4 granularity
    const float4 m4 = reinterpret_cast<const float4*>(wmu)[idx];
    const float4 r4 = reinterpret_cast<const float4*>(wrho)[idx];
    uint4 w;
    w.x = (bf16_rne(softplus_f(r4.x)) << 16) | bf16_rne(m4.x);
    w.y = (bf16_rne(softplus_f(r4.y)) << 16) | bf16_rne(m4.y);
    w.z = (bf16_rne(softplus_f(r4.z)) << 16) | bf16_rne(m4.z);
    w.w = (bf16_rne(softplus_f(r4.w)) << 16) | bf16_rne(m4.w);
    reinterpret_cast<uint4*>(qm)[idx] = w;

    if (blockIdx.x < 4) {
        const int o = blockIdx.x * 256 + threadIdx.x;  // 0..1023
        bsp[o] = softplus_f(brho[o]);
    }
}

// ---------- pass 2: main stream via global_load_lds pipeline ----------
// Wave owns (b, o0..o0+15). x row in registers. Per iteration: consume slot
// (ds_read_b128), restage next row (8x gl_lds, 16B wide), counted vmcnt(8)
// waits keep one full row in flight at all times. Wave-private LDS: no
// barriers, no cross-wave hazards.
__global__ __launch_bounds__(256) void bayes_main_kernel(
    const float* __restrict__ x,
    const unsigned* __restrict__ qm,
    const float* __restrict__ bmu,
    const float* __restrict__ bsp,
    const float* __restrict__ epsw,
    const float* __restrict__ epsb,
    float* __restrict__ out)
{
    __shared__ __align__(16) uint8_t smem[4][DEPTH][8192]; // 64 KB/block
    const int w    = threadIdx.x >> 6;
    const int lane = threadIdx.x & 63;
    const int wid  = blockIdx.x * 4 + w;
    const int b  = wid >> 6;           // 0..127
    const int o0 = (wid & 63) * NO;    // 0..1008

    // x[b,:] -> 16 registers/lane (plain loads; drained by first vmcnt(8)).
    const float4* __restrict__ x4 = reinterpret_cast<const float4*>(x + (size_t)b * DIN);
    float xv[16];
    #pragma unroll
    for (int k = 0; k < 4; ++k) {
        const float4 t = x4[lane + (k << 6)];
        xv[4*k+0] = t.x; xv[4*k+1] = t.y; xv[4*k+2] = t.z; xv[4*k+3] = t.w;
    }

    const float*    erow = epsw + ((size_t)b * DOUT + o0) * DIN;
    const unsigned* qrow = qm + (size_t)o0 * DIN;

    // Stage row r (eps 4KB + qm 4KB) into slot s: 8 x gl_lds (1 KB each).
    auto stage_row = [&](int r, int s) {
        const float*    eg = erow + (size_t)r * DIN + lane * 4;
        const unsigned* qg = qrow + (size_t)r * DIN + lane * 4;
        uint8_t* le = &smem[w][s][0];
        uint8_t* lq = &smem[w][s][4096];
        #pragma unroll
        for (int t = 0; t < 4; ++t) {
            stage16(eg + t * 256, le + t * 1024);
            stage16(qg + t * 256, lq + t * 1024);
        }
    };

    stage_row(0, 0);
    stage_row(1, 1);

    float acc[NO];

    #pragma unroll
    for (int r = 0; r < NO; ++r) {
        const int s = r & 1;
        // Row r complete when <= 8 gl_lds outstanding (row r+1 stays in
        // flight). Last iteration: nothing ahead, drain fully.
        if (r < NO - 1) asm volatile("s_waitcnt vmcnt(8)" ::: "memory");
        else            asm volatile("s_waitcnt vmcnt(0)" ::: "memory");
        __builtin_amdgcn_sched_barrier(0);

        // LDS -> VGPR (ds_read_b128, conflict-free linear layout).
        const float4* __restrict__ eL = reinterpret_cast<const float4*>(&smem[w][s][0]);
        const uint4*  __restrict__ qL = reinterpret_cast<const uint4*>(&smem[w][s][4096]);
        float4 ee[4]; uint4 ww[4];
        #pragma unroll
        for (int k = 0; k < 4; ++k) {
            ee[k] = eL[lane + (k << 6)];
            ww[k] = qL[lane + (k << 6)];
        }
        // All ds_reads landed in VGPRs -> slot is free to overwrite.
        asm volatile("s_waitcnt lgkmcnt(0)" ::: "memory");
        __builtin_amdgcn_sched_barrier(0);
        if (r + DEPTH < NO) stage_row(r + DEPTH, s);

        float a = 0.0f;
        #pragma unroll
        for (int k = 0; k < 4; ++k) {
            a = fmaf(xv[4*k+0], fmaf(__uint_as_float(ww[k].x & 0xffff0000u), ee[k].x,
                                     __uint_as_float(ww[k].x << 16)), a);
            a = fmaf(xv[4*k+1], fmaf(__uint_as_float(ww[k].y & 0xffff0000u), ee[k].y,
                                     __uint_as_float(ww[k].y << 16)), a);
            a = fmaf(xv[4*k+2], fmaf(__uint_as_float(ww[k].z & 0xffff0000u), ee[k].z,
                                     __uint_as_float(ww[k].z << 16)), a);
            a = fmaf(xv[4*k+3], fmaf(__uint_as_float(ww[k].w & 0xffff0000u), ee[k].w,
                                     __uint_as_float(ww[k].w << 16)), a);
        }
        acc[r] = a;
    }

    // Butterfly reductions (after the loop; no vmem mixing with the pipeline).
    #pragma unroll
    for (int r = 0; r < NO; ++r) {
        #pragma unroll
        for (int off = 32; off >= 1; off >>= 1)
            acc[r] += __shfl_xor(acc[r], off, 64);
    }

    if (lane == 0) {
        const size_t row0 = (size_t)b * DOUT + o0;
        #pragma unroll
        for (int r = 0; r < NO; ++r) {
            const int o = o0 + r;
            out[row0 + r] = acc[r] + fmaf(bsp[o], epsb[row0 + r], bmu[o]);
        }
    }
}

extern "C" void kernel_launch(void* const* d_in, const int* in_sizes, int n_in,
                              void* d_out, int out_size, void* d_ws, size_t ws_size,
                              hipStream_t stream) {
    const float* x    = (const float*)d_in[0];
    const float* wmu  = (const float*)d_in[1];
    const float* wrho = (const float*)d_in[2];
    const float* bmu  = (const float*)d_in[3];
    const float* brho = (const float*)d_in[4];
    const float* epsw = (const float*)d_in[5];
    const float* epsb = (const float*)d_in[6];
    float* out = (float*)d_out;

    unsigned* qm  = (unsigned*)d_ws;                                              // 4 MB
    float*    bsp = (float*)((char*)d_ws + (size_t)DOUT * DIN * sizeof(unsigned)); // 4 KB

    pack_qm_kernel<<<(DOUT * DIN / 4) / 256, 256, 0, stream>>>(wmu, wrho, brho, qm, bsp);

    // waves = BATCH * (DOUT/NO) = 128*64 = 8192; 4 waves per block.
    bayes_main_kernel<<<8192 / 4, 256, 0, stream>>>(x, qm, bmu, bsp, epsw, epsb, out);
}